// Round 3
// baseline (324.192 us; speedup 1.0000x reference)
//
#include <hip/hip_runtime.h>

#define B_ROWS   16384
#define K_NB     64
#define D_DIM    256
#define TWO_D    512
#define R_BLK    8          // rows per block
#define THREADS  256

__global__ __launch_bounds__(THREADS, 2)   // allow high VGPR: need 16 float4 gathers in flight
void easyrec_fused(const int* __restrict__ nodes_u,
                   const int* __restrict__ nodes_v,
                   const int* __restrict__ neighbors,
                   const int* __restrict__ neighbor_counts,
                   const float* __restrict__ u2e,
                   const float* __restrict__ v2e,
                   const float* __restrict__ W,      // [D, 2D] row-major
                   const float* __restrict__ bias,   // [D]
                   float* __restrict__ out)          // [B]
{
    __shared__ __align__(16) int nbr_lds[R_BLK * K_NB];     // 2 KB
    __shared__ __align__(16) float cat_lds[R_BLK][TWO_D];   // 16 KB: [self | nmean]
    __shared__ float red_lds[R_BLK * 4];
    __shared__ float selfdot_lds[R_BLK];
    __shared__ float bdot_lds[R_BLK];

    const int t    = threadIdx.x;
    const int wave = t >> 6;
    const int lane = t & 63;
    const int row0 = blockIdx.x * R_BLK;

    // ---- stage neighbor indices for the 8 rows (512 ints, coalesced) ----
    nbr_lds[t]           = neighbors[(size_t)row0 * K_NB + t];
    nbr_lds[t + THREADS] = neighbors[(size_t)row0 * K_NB + t + THREADS];
    __syncthreads();

    // ---- prologue: self/v/bias work done up front so those regs are dead in the gather loop ----
    const int r0 = wave, r1 = wave + 4;
    const int cnt0 = __builtin_amdgcn_readfirstlane(neighbor_counts[row0 + r0]);
    const int cnt1 = __builtin_amdgcn_readfirstlane(neighbor_counts[row0 + r1]);
    {
        const float4 b4 = *(const float4*)(bias + 4 * lane);
        #pragma unroll
        for (int rr = 0; rr < 2; ++rr) {
            const int r  = (rr == 0) ? r0 : r1;
            const int nu = __builtin_amdgcn_readfirstlane(nodes_u[row0 + r]);
            const int nv = __builtin_amdgcn_readfirstlane(nodes_v[row0 + r]);
            const float4 self4 = *(const float4*)(u2e + (size_t)nu * D_DIM + 4 * lane);
            const float4 v4    = *(const float4*)(v2e + (size_t)nv * D_DIM + 4 * lane);
            *(float4*)(&cat_lds[r][4 * lane]) = self4;
            float sv = self4.x * v4.x + self4.y * v4.y + self4.z * v4.z + self4.w * v4.w;
            float bv = b4.x * v4.x + b4.y * v4.y + b4.z * v4.z + b4.w * v4.w;
            #pragma unroll
            for (int off = 32; off > 0; off >>= 1) {
                sv += __shfl_xor(sv, off, 64);
                bv += __shfl_xor(bv, off, 64);
            }
            if (lane == 0) { selfdot_lds[r] = sv; bdot_lds[r] = bv; }
        }
    }

    // ---- phase 1: both rows gathered in the same k-loop -> 16 float4 loads in flight ----
    // neighbors[] entries are always valid indices; over-read past cnt and mask the accumulate.
    {
        const int base0 = r0 * K_NB, base1 = r1 * K_NB;
        const int kmax0 = (cnt0 + 7) & ~7;
        const int kmax1 = (cnt1 + 7) & ~7;
        const int kmax  = kmax0 > kmax1 ? kmax0 : kmax1;
        const int col   = 4 * lane;

        float4 acc0 = make_float4(0.f, 0.f, 0.f, 0.f);
        float4 acc1 = make_float4(0.f, 0.f, 0.f, 0.f);

        for (int k = 0; k < kmax; k += 8) {
            const bool doA = k < kmax0;   // wave-uniform
            const bool doB = k < kmax1;
            float4 na[8], nb[8];
            if (doA) {
                const int4 ia = *(const int4*)&nbr_lds[base0 + k];
                const int4 ib = *(const int4*)&nbr_lds[base0 + k + 4];
                na[0] = *(const float4*)(u2e + (size_t)ia.x * D_DIM + col);
                na[1] = *(const float4*)(u2e + (size_t)ia.y * D_DIM + col);
                na[2] = *(const float4*)(u2e + (size_t)ia.z * D_DIM + col);
                na[3] = *(const float4*)(u2e + (size_t)ia.w * D_DIM + col);
                na[4] = *(const float4*)(u2e + (size_t)ib.x * D_DIM + col);
                na[5] = *(const float4*)(u2e + (size_t)ib.y * D_DIM + col);
                na[6] = *(const float4*)(u2e + (size_t)ib.z * D_DIM + col);
                na[7] = *(const float4*)(u2e + (size_t)ib.w * D_DIM + col);
            }
            if (doB) {
                const int4 ia = *(const int4*)&nbr_lds[base1 + k];
                const int4 ib = *(const int4*)&nbr_lds[base1 + k + 4];
                nb[0] = *(const float4*)(u2e + (size_t)ia.x * D_DIM + col);
                nb[1] = *(const float4*)(u2e + (size_t)ia.y * D_DIM + col);
                nb[2] = *(const float4*)(u2e + (size_t)ia.z * D_DIM + col);
                nb[3] = *(const float4*)(u2e + (size_t)ia.w * D_DIM + col);
                nb[4] = *(const float4*)(u2e + (size_t)ib.x * D_DIM + col);
                nb[5] = *(const float4*)(u2e + (size_t)ib.y * D_DIM + col);
                nb[6] = *(const float4*)(u2e + (size_t)ib.z * D_DIM + col);
                nb[7] = *(const float4*)(u2e + (size_t)ib.w * D_DIM + col);
            }
            if (doA) {
                if (k + 8 <= cnt0) {
                    #pragma unroll
                    for (int j = 0; j < 8; ++j) {
                        acc0.x += na[j].x; acc0.y += na[j].y;
                        acc0.z += na[j].z; acc0.w += na[j].w;
                    }
                } else {
                    #pragma unroll
                    for (int j = 0; j < 8; ++j) {
                        const float m = (k + j < cnt0) ? 1.f : 0.f;
                        acc0.x += na[j].x * m; acc0.y += na[j].y * m;
                        acc0.z += na[j].z * m; acc0.w += na[j].w * m;
                    }
                }
            }
            if (doB) {
                if (k + 8 <= cnt1) {
                    #pragma unroll
                    for (int j = 0; j < 8; ++j) {
                        acc1.x += nb[j].x; acc1.y += nb[j].y;
                        acc1.z += nb[j].z; acc1.w += nb[j].w;
                    }
                } else {
                    #pragma unroll
                    for (int j = 0; j < 8; ++j) {
                        const float m = (k + j < cnt1) ? 1.f : 0.f;
                        acc1.x += nb[j].x * m; acc1.y += nb[j].y * m;
                        acc1.z += nb[j].z * m; acc1.w += nb[j].w * m;
                    }
                }
            }
        }

        const float inv0 = 1.0f / (float)(cnt0 > 0 ? cnt0 : 1);
        const float inv1 = 1.0f / (float)(cnt1 > 0 ? cnt1 : 1);
        *(float4*)(&cat_lds[r0][D_DIM + col]) =
            make_float4(acc0.x * inv0, acc0.y * inv0, acc0.z * inv0, acc0.w * inv0);
        *(float4*)(&cat_lds[r1][D_DIM + col]) =
            make_float4(acc1.x * inv1, acc1.y * inv1, acc1.z * inv1, acc1.w * inv1);
    }
    __syncthreads();

    // ---- phase 2: t_j = sum_d W[d, j] * v[d]; thread t owns j = 2t, 2t+1 for all 8 rows ----
    const float* vrow[R_BLK];
    #pragma unroll
    for (int r = 0; r < R_BLK; ++r) {
        const int nv = __builtin_amdgcn_readfirstlane(nodes_v[row0 + r]);
        vrow[r] = v2e + (size_t)nv * D_DIM;
    }

    float2 acc2[R_BLK];
    #pragma unroll
    for (int r = 0; r < R_BLK; ++r) acc2[r] = make_float2(0.f, 0.f);

    for (int d = 0; d < D_DIM; d += 4) {
        float4 vq[R_BLK];
        #pragma unroll
        for (int r = 0; r < R_BLK; ++r) vq[r] = *(const float4*)(vrow[r] + d);

        #pragma unroll
        for (int dd = 0; dd < 4; ++dd) {
            const float2 wq = *(const float2*)(W + (size_t)(d + dd) * TWO_D + 2 * t);
            #pragma unroll
            for (int r = 0; r < R_BLK; ++r) {
                const float vs = (dd == 0) ? vq[r].x : (dd == 1) ? vq[r].y
                               : (dd == 2) ? vq[r].z : vq[r].w;
                acc2[r].x += wq.x * vs;
                acc2[r].y += wq.y * vs;
            }
        }
    }

    // ---- epilogue: score = sum_j cat[j] * t_j  (+ b·v), reduce across block ----
    #pragma unroll
    for (int r = 0; r < R_BLK; ++r) {
        const float2 c2 = *(const float2*)(&cat_lds[r][2 * t]);
        float p = c2.x * acc2[r].x + c2.y * acc2[r].y;
        #pragma unroll
        for (int off = 32; off > 0; off >>= 1) p += __shfl_xor(p, off, 64);
        if (lane == 0) red_lds[r * 4 + wave] = p;
    }
    __syncthreads();

    if (t < R_BLK) {
        const int row = row0 + t;
        const int cnt = neighbor_counts[row];
        float s;
        if (cnt > 0) {
            s = red_lds[t * 4 + 0] + red_lds[t * 4 + 1]
              + red_lds[t * 4 + 2] + red_lds[t * 4 + 3] + bdot_lds[t];
        } else {
            s = selfdot_lds[t];
        }
        out[row] = s;
    }
}

extern "C" void kernel_launch(void* const* d_in, const int* in_sizes, int n_in,
                              void* d_out, int out_size, void* d_ws, size_t ws_size,
                              hipStream_t stream) {
    const int*   nodes_u         = (const int*)d_in[0];
    const int*   nodes_v         = (const int*)d_in[1];
    const int*   neighbors       = (const int*)d_in[2];
    const int*   neighbor_counts = (const int*)d_in[3];
    const float* u2e             = (const float*)d_in[4];
    const float* v2e             = (const float*)d_in[5];
    const float* W               = (const float*)d_in[6];
    const float* bias            = (const float*)d_in[7];
    float*       out             = (float*)d_out;

    const int blocks = B_ROWS / R_BLK;   // 2048
    easyrec_fused<<<blocks, THREADS, 0, stream>>>(
        nodes_u, nodes_v, neighbors, neighbor_counts, u2e, v2e, W, bias, out);
}